// Round 13
// baseline (437.332 us; speedup 1.0000x reference)
//
#include <hip/hip_runtime.h>

#define NEG_SLOPE 0.2f
#define EPSV 1e-16f

typedef float f32x4 __attribute__((ext_vector_type(4)));
typedef float f32x2 __attribute__((ext_vector_type(2)));
typedef short s16x2 __attribute__((ext_vector_type(2)));
typedef unsigned u32x2 __attribute__((ext_vector_type(2)));

// Monotone f32 <-> u32 mapping so atomicMax(u32) implements float max.
__device__ __forceinline__ unsigned fenc(float f) {
    unsigned b = __float_as_uint(f);
    return b ^ ((b & 0x80000000u) ? 0xFFFFFFFFu : 0x80000000u);
}
__device__ __forceinline__ float fdec(unsigned u) {
    unsigned b = (u & 0x80000000u) ? (u ^ 0x80000000u) : ~u;
    return __uint_as_float(b);
}
#define FENC_NEG_INF 0x007FFFFFu   // fenc(-inf)

__device__ __forceinline__ unsigned f32_to_bf16_rne(float f) {
    unsigned u = __float_as_uint(f);
    unsigned lsb = (u >> 16) & 1u;
    return (u + 0x7FFFu + lsb) >> 16;   // values are positive finite
}

// One packed atomic adds 2 bf16 lanes: native GLOBAL_ATOMIC_PK_ADD_BF16.
__device__ __forceinline__ void pk_atomic_add_bf16(unsigned* addr, float a, float b) {
#if __has_builtin(__builtin_amdgcn_global_atomic_fadd_v2bf16)
    s16x2 v;
    v.x = (short)f32_to_bf16_rne(a);
    v.y = (short)f32_to_bf16_rne(b);
    typedef __attribute__((address_space(1))) s16x2 gs16x2;
    __builtin_amdgcn_global_atomic_fadd_v2bf16((gs16x2*)(void*)addr, v);
#else
    unsigned old = *addr, assumed;
    do {
        assumed = old;
        float lo = __uint_as_float((assumed & 0xFFFFu) << 16) + a;
        float hi = __uint_as_float(assumed & 0xFFFF0000u) + b;
        unsigned nv = (f32_to_bf16_rne(hi) << 16) | (f32_to_bf16_rne(lo) & 0xFFFFu);
        old = atomicCAS(addr, assumed, nv);
    } while (old != assumed);
#endif
}

// Detect int64 vs int32 edge_index on device.
__global__ void detect_idx_kernel(const unsigned* __restrict__ ei32,
                                  int* __restrict__ flag) {
    __shared__ int anynz;
    if (threadIdx.x == 0) anynz = 0;
    __syncthreads();
    unsigned v = ei32[2 * threadIdx.x + 1];
    if (v != 0u) anynz = 1;
    __syncthreads();
    if (threadIdx.x == 0) *flag = (anynz ? 0 : 1);   // 1 => int64
}

// nt index load (r9-proven).
__device__ __forceinline__ int load_idx(const void* ei, int is64, size_t k) {
    if (is64) return (int)__builtin_nontemporal_load(&((const long long*)ei)[k]);
    return __builtin_nontemporal_load(&((const int*)ei)[k]);
}

// K1: per-node logits per head; zero pk nsum; init gmax.
__global__ void node_scores_kernel(const float* __restrict__ nf,
                                   const float* __restrict__ sfs,
                                   const float* __restrict__ sft,
                                   float* __restrict__ ss,
                                   float* __restrict__ st,
                                   unsigned* __restrict__ nsum_zero,
                                   unsigned* __restrict__ gmax,
                                   int NH, int nzero) {
    int i = blockIdx.x * blockDim.x + threadIdx.x;
    if (i >= NH) return;
    if (i == 0) *gmax = FENC_NEG_INF;
    for (int k = i; k < nzero; k += NH) nsum_zero[k] = 0u;
    int h = i & 3;
    const float4* __restrict__ row = (const float4*)(nf + (size_t)i * 32);
    const float4* __restrict__ as  = (const float4*)(sfs + h * 32);
    const float4* __restrict__ at  = (const float4*)(sft + h * 32);
    float accs = 0.f, acct = 0.f;
#pragma unroll
    for (int q = 0; q < 8; ++q) {
        float4 v = row[q];
        float4 a = as[q];
        float4 b = at[q];
        accs += v.x * a.x + v.y * a.y + v.z * a.z + v.w * a.w;
        acct += v.x * b.x + v.y * b.y + v.z * b.z + v.w * b.w;
    }
    ss[i] = accs;
    st[i] = acct;
}

// K2 (r9-exact): per (edge, head-pair): p = exp(leaky_relu(ss+st)) -> pbuf
// (nt, 8B), ONE pk bf16 atomic into nsum_pk; track running max.
// Identity (validated r6+): exp(lr-c)/(S+eps) == exp(lr)/(S'+eps*e^c).
__global__ void edge_exp_sum_pk_kernel(const void* __restrict__ ei,
                                       const int* __restrict__ flag,
                                       const float* __restrict__ ss,
                                       const float* __restrict__ st,
                                       float* __restrict__ pbuf,
                                       unsigned* __restrict__ nsum_pk,
                                       unsigned* __restrict__ gmax,
                                       int E) {
    __shared__ float red[256];
    int is64 = *flag;
    int n2 = E * 2;
    int stride = gridDim.x * blockDim.x;
    float lmax = -__builtin_inff();
    for (int i = blockIdx.x * blockDim.x + threadIdx.x; i < n2; i += stride) {
        int e = i >> 1, hp = i & 1;
        int trg = load_idx(ei, is64, e);
        int src = load_idx(ei, is64, (size_t)E + e);
        f32x2 a = *(const f32x2*)(ss + (size_t)src * 4 + hp * 2);
        f32x2 b = *(const f32x2*)(st + (size_t)trg * 4 + hp * 2);
        float s0 = a.x + b.x, s1 = a.y + b.y;
        float lr0 = s0 > 0.f ? s0 : NEG_SLOPE * s0;
        float lr1 = s1 > 0.f ? s1 : NEG_SLOPE * s1;
        lmax = fmaxf(lmax, fmaxf(lr0, lr1));
        float p0 = __expf(lr0), p1 = __expf(lr1);
        f32x2 pv; pv.x = p0; pv.y = p1;
        __builtin_nontemporal_store(pv, (f32x2*)(pbuf + (size_t)e * 4 + hp * 2));
        pk_atomic_add_bf16(nsum_pk + (size_t)trg * 2 + hp, p0, p1);
    }
    red[threadIdx.x] = lmax;
    __syncthreads();
    for (int off = 128; off > 0; off >>= 1) {
        if (threadIdx.x < off)
            red[threadIdx.x] = fmaxf(red[threadIdx.x], red[threadIdx.x + off]);
        __syncthreads();
    }
    if (threadIdx.x == 0) atomicMax(gmax, fenc(red[0]));
}

// K3 (r9-exact): att = p / (bf16_decode(nsum) + eps*e^c); float4 in, nt out.
__global__ void att_pk_kernel(const void* __restrict__ ei,
                              const int* __restrict__ flag,
                              const float* __restrict__ pbuf,
                              const unsigned* __restrict__ nsum_pk,
                              const unsigned* __restrict__ gmax,
                              float* __restrict__ out,
                              int E) {
    int is64 = *flag;
    float de = EPSV * __expf(fdec(*gmax));
    int stride = gridDim.x * blockDim.x;
    for (int e = blockIdx.x * blockDim.x + threadIdx.x; e < E; e += stride) {
        int trg = load_idx(ei, is64, e);
        u32x2 u = *(const u32x2*)(nsum_pk + (size_t)trg * 2);
        f32x4 d;
        d.x = __uint_as_float((u.x & 0xFFFFu) << 16);
        d.y = __uint_as_float(u.x & 0xFFFF0000u);
        d.z = __uint_as_float((u.y & 0xFFFFu) << 16);
        d.w = __uint_as_float(u.y & 0xFFFF0000u);
        f32x4 p = __builtin_nontemporal_load((const f32x4*)(pbuf + (size_t)e * 4));
        f32x4 a = p / (d + de);
        __builtin_nontemporal_store(a, (f32x4*)(out + (size_t)e * 4));
    }
}

// K4 (r13 change): CHUNKED feature gather. npass passes; pass k writes only
// edges whose src falls in node chunk k (3.2MB < 4MB per-XCD L2), so gather
// reads hit L2 regardless of L3 thrash from the 410MB write stream.
// Writes stay full-line (32 lanes x 16B contiguous per edge); reads CACHED.
__global__ void gather_feat_chunked_kernel(const void* __restrict__ ei,
                                           const int* __restrict__ flag,
                                           const f32x4* __restrict__ nf4,
                                           f32x4* __restrict__ out4,
                                           int E, int chunk, int npass) {
    int is64 = *flag;
    int n = E * 32;
    int stride = gridDim.x * blockDim.x;
    int lo = 0;
    for (int pass = 0; pass < npass; ++pass, lo += chunk) {
        int hi = lo + chunk;
        for (int t = blockIdx.x * blockDim.x + threadIdx.x; t < n; t += stride) {
            int e = t >> 5, q = t & 31;
            int src = load_idx(ei, is64, (size_t)E + e);
            if (src >= lo && src < hi) {
                f32x4 v = nf4[(size_t)src * 32 + q];   // cached: L2-resident chunk
                __builtin_nontemporal_store(v, &out4[(size_t)e * 32 + q]);
            }
        }
    }
}

// ---------- fallback (ws too small for pbuf): recompute pipeline ----------
__device__ __forceinline__ float edge_lr_rc(const void* ei, int is64,
                                            const float* ss, const float* st,
                                            int E, int e, int h, int* trg_out) {
    int trg = load_idx(ei, is64, e);
    int src = load_idx(ei, is64, (size_t)E + e);
    if (trg_out) *trg_out = trg;
    float s = ss[src * 4 + h] + st[trg * 4 + h];
    return s > 0.f ? s : NEG_SLOPE * s;
}

__global__ void zero_fb_kernel(float* __restrict__ nsum, int n) {
    int i = blockIdx.x * blockDim.x + threadIdx.x;
    if (i < n) nsum[i] = 0.f;
}

__global__ void edge_exp_sum_fb_kernel(const void* __restrict__ ei,
                                       const int* __restrict__ flag,
                                       const float* __restrict__ ss,
                                       const float* __restrict__ st,
                                       float* __restrict__ nsum,
                                       unsigned* __restrict__ gmax, int E) {
    __shared__ float red[256];
    int is64 = *flag;
    int n4 = E * 4;
    int stride = gridDim.x * blockDim.x;
    float lmax = -__builtin_inff();
    for (int i = blockIdx.x * blockDim.x + threadIdx.x; i < n4; i += stride) {
        int trg;
        float lr = edge_lr_rc(ei, is64, ss, st, E, i >> 2, i & 3, &trg);
        lmax = fmaxf(lmax, lr);
        atomicAdd(&nsum[trg * 4 + (i & 3)], __expf(lr));
    }
    red[threadIdx.x] = lmax;
    __syncthreads();
    for (int off = 128; off > 0; off >>= 1) {
        if (threadIdx.x < off)
            red[threadIdx.x] = fmaxf(red[threadIdx.x], red[threadIdx.x + off]);
        __syncthreads();
    }
    if (threadIdx.x == 0) atomicMax(gmax, fenc(red[0]));
}

__global__ void att_fb_kernel(const void* __restrict__ ei,
                              const int* __restrict__ flag,
                              const float* __restrict__ ss,
                              const float* __restrict__ st,
                              const unsigned* __restrict__ gmax,
                              const float* __restrict__ nsum,
                              float* __restrict__ out, int E) {
    int i = blockIdx.x * blockDim.x + threadIdx.x;
    if (i >= E * 4) return;
    int is64 = *flag;
    float de = EPSV * __expf(fdec(*gmax));
    int trg;
    float lr = edge_lr_rc(ei, is64, ss, st, E, i >> 2, i & 3, &trg);
    float a = __expf(lr) / (nsum[trg * 4 + (i & 3)] + de);
    __builtin_nontemporal_store(a, &out[i]);
}

extern "C" void kernel_launch(void* const* d_in, const int* in_sizes, int n_in,
                              void* d_out, int out_size, void* d_ws, size_t ws_size,
                              hipStream_t stream) {
    const float* nf  = (const float*)d_in[0];
    const float* sfs = (const float*)d_in[1];
    const float* sft = (const float*)d_in[2];
    const void*  ei  = d_in[3];

    const int NH = in_sizes[0] / 32;   // N*H (F = 32)
    const int N  = NH / 4;
    const int E  = in_sizes[3] / 2;

    float* out = (float*)d_out;
    float* ws  = (float*)d_ws;

    // Layout: ss[NH] | st[NH] | flag,gmax,pad,pad | pbuf[E*4] | nsum_pk[N*2 u32]
    float*    ss      = ws;
    float*    st      = ws + NH;
    int*      flag    = (int*)(ws + 2 * (size_t)NH);
    unsigned* gmax    = (unsigned*)(flag + 1);
    float*    pbuf    = ws + 2 * (size_t)NH + 4;
    unsigned* nsum_pk = (unsigned*)(pbuf + (size_t)E * 4);

    size_t need = ((size_t)2 * NH + 4 + (size_t)E * 4 + (size_t)N * 2) * 4;
    bool lean = ws_size >= need;

    const int B = 256;

    // Chunk sizing: per-XCD L2 = 4MB; rows are 512B. 6250 nodes = 3.2MB.
    const int NPASS = 8;
    const int CHUNK = (N + NPASS - 1) / NPASS;

    detect_idx_kernel<<<1, 256, 0, stream>>>((const unsigned*)ei, flag);

    if (lean) {
        node_scores_kernel<<<(NH + B - 1) / B, B, 0, stream>>>(
            nf, sfs, sft, ss, st, nsum_pk, gmax, NH, N * 2);
        edge_exp_sum_pk_kernel<<<2048, B, 0, stream>>>(ei, flag, ss, st, pbuf,
                                                       nsum_pk, gmax, E);
        att_pk_kernel<<<2048, B, 0, stream>>>(ei, flag, pbuf, nsum_pk, gmax,
                                              out, E);
        gather_feat_chunked_kernel<<<4096, B, 0, stream>>>(
            ei, flag, (const f32x4*)nf, (f32x4*)(out + (size_t)E * 4),
            E, CHUNK, NPASS);
    } else {
        // minimal-ws fallback: f32 nsum right after gmax
        float* nsum_fb = (float*)(gmax + 1);
        node_scores_kernel<<<(NH + B - 1) / B, B, 0, stream>>>(
            nf, sfs, sft, ss, st, (unsigned*)nsum_fb, gmax, NH, 0);
        zero_fb_kernel<<<(NH + B - 1) / B, B, 0, stream>>>(nsum_fb, NH);
        edge_exp_sum_fb_kernel<<<2048, B, 0, stream>>>(ei, flag, ss, st,
                                                       nsum_fb, gmax, E);
        att_fb_kernel<<<(E * 4 + B - 1) / B, B, 0, stream>>>(ei, flag, ss, st,
                                                             gmax, nsum_fb, out, E);
        gather_feat_chunked_kernel<<<4096, B, 0, stream>>>(
            ei, flag, (const f32x4*)nf, (f32x4*)(out + (size_t)E * 4),
            E, CHUNK, NPASS);
    }
}

// Round 14
// 219.810 us; speedup vs baseline: 1.9896x; 1.9896x over previous
//
#include <hip/hip_runtime.h>

#define NEG_SLOPE 0.2f
#define EPSV 1e-16f
#define NBMAX 256
#define BSHIFT 8   // bucket = src >> 8 (256 nodes = 128KB of rows)

typedef float f32x4 __attribute__((ext_vector_type(4)));
typedef float f32x2 __attribute__((ext_vector_type(2)));
typedef short s16x2 __attribute__((ext_vector_type(2)));
typedef unsigned u32x2 __attribute__((ext_vector_type(2)));

__device__ __forceinline__ unsigned fenc(float f) {
    unsigned b = __float_as_uint(f);
    return b ^ ((b & 0x80000000u) ? 0xFFFFFFFFu : 0x80000000u);
}
__device__ __forceinline__ float fdec(unsigned u) {
    unsigned b = (u & 0x80000000u) ? (u ^ 0x80000000u) : ~u;
    return __uint_as_float(b);
}
#define FENC_NEG_INF 0x007FFFFFu

__device__ __forceinline__ unsigned f32_to_bf16_rne(float f) {
    unsigned u = __float_as_uint(f);
    unsigned lsb = (u >> 16) & 1u;
    return (u + 0x7FFFu + lsb) >> 16;
}

__device__ __forceinline__ void pk_atomic_add_bf16(unsigned* addr, float a, float b) {
#if __has_builtin(__builtin_amdgcn_global_atomic_fadd_v2bf16)
    s16x2 v;
    v.x = (short)f32_to_bf16_rne(a);
    v.y = (short)f32_to_bf16_rne(b);
    typedef __attribute__((address_space(1))) s16x2 gs16x2;
    __builtin_amdgcn_global_atomic_fadd_v2bf16((gs16x2*)(void*)addr, v);
#else
    unsigned old = *addr, assumed;
    do {
        assumed = old;
        float lo = __uint_as_float((assumed & 0xFFFFu) << 16) + a;
        float hi = __uint_as_float(assumed & 0xFFFF0000u) + b;
        unsigned nv = (f32_to_bf16_rne(hi) << 16) | (f32_to_bf16_rne(lo) & 0xFFFFu);
        old = atomicCAS(addr, assumed, nv);
    } while (old != assumed);
#endif
}

// Detect int64 vs int32 edge_index; also zero the bucket histogram.
__global__ void detect_idx_kernel(const unsigned* __restrict__ ei32,
                                  int* __restrict__ flag,
                                  unsigned* __restrict__ bhist) {
    __shared__ int anynz;
    if (threadIdx.x == 0) anynz = 0;
    __syncthreads();
    unsigned v = ei32[2 * threadIdx.x + 1];
    if (v != 0u) anynz = 1;
    if (threadIdx.x < NBMAX) bhist[threadIdx.x] = 0u;
    __syncthreads();
    if (threadIdx.x == 0) *flag = (anynz ? 0 : 1);
}

__device__ __forceinline__ int load_idx(const void* ei, int is64, size_t k) {
    if (is64) return (int)__builtin_nontemporal_load(&((const long long*)ei)[k]);
    return __builtin_nontemporal_load(&((const int*)ei)[k]);
}

// K1: per-node logits per head; zero pk nsum; init gmax.
__global__ void node_scores_kernel(const float* __restrict__ nf,
                                   const float* __restrict__ sfs,
                                   const float* __restrict__ sft,
                                   float* __restrict__ ss,
                                   float* __restrict__ st,
                                   unsigned* __restrict__ nsum_zero,
                                   unsigned* __restrict__ gmax,
                                   int NH, int nzero) {
    int i = blockIdx.x * blockDim.x + threadIdx.x;
    if (i >= NH) return;
    if (i == 0) *gmax = FENC_NEG_INF;
    for (int k = i; k < nzero; k += NH) nsum_zero[k] = 0u;
    int h = i & 3;
    const float4* __restrict__ row = (const float4*)(nf + (size_t)i * 32);
    const float4* __restrict__ as  = (const float4*)(sfs + h * 32);
    const float4* __restrict__ at  = (const float4*)(sft + h * 32);
    float accs = 0.f, acct = 0.f;
#pragma unroll
    for (int q = 0; q < 8; ++q) {
        float4 v = row[q];
        float4 a = as[q];
        float4 b = at[q];
        accs += v.x * a.x + v.y * a.y + v.z * a.z + v.w * a.w;
        acct += v.x * b.x + v.y * b.y + v.z * b.z + v.w * b.w;
    }
    ss[i] = accs;
    st[i] = acct;
}

// ---- binning (src-bucket counting sort; perm order races are benign: each
// perm slot written once, each edge appears once -> output independent) ----
__global__ void bin_hist_kernel(const void* __restrict__ ei,
                                const int* __restrict__ flag,
                                unsigned* __restrict__ bhist, int E) {
    __shared__ unsigned lh[NBMAX];
    for (int i = threadIdx.x; i < NBMAX; i += blockDim.x) lh[i] = 0u;
    __syncthreads();
    int is64 = *flag;
    int per = (E + gridDim.x - 1) / gridDim.x;
    int s = blockIdx.x * per;
    int en = s + per < E ? s + per : E;
    for (int e = s + threadIdx.x; e < en; e += blockDim.x) {
        int src = load_idx(ei, is64, (size_t)E + e);
        atomicAdd(&lh[src >> BSHIFT], 1u);
    }
    __syncthreads();
    for (int i = threadIdx.x; i < NBMAX; i += blockDim.x)
        if (lh[i]) atomicAdd(&bhist[i], lh[i]);
}

__global__ void bin_scan_kernel(const unsigned* __restrict__ bhist,
                                unsigned* __restrict__ bstart,
                                unsigned* __restrict__ bcursor, int nb) {
    if (threadIdx.x == 0) {
        unsigned acc = 0;
        for (int c = 0; c < nb; ++c) {
            bstart[c] = acc;
            bcursor[c] = acc;
            acc += bhist[c];
        }
        bstart[nb] = acc;
    }
}

__global__ void bin_scatter_kernel(const void* __restrict__ ei,
                                   const int* __restrict__ flag,
                                   unsigned* __restrict__ bcursor,
                                   int* __restrict__ perm,
                                   int* __restrict__ ssrc, int E) {
    __shared__ unsigned lh[NBMAX], lbase[NBMAX], lcur[NBMAX];
    for (int i = threadIdx.x; i < NBMAX; i += blockDim.x) { lh[i] = 0u; lcur[i] = 0u; }
    __syncthreads();
    int is64 = *flag;
    int per = (E + gridDim.x - 1) / gridDim.x;
    int s = blockIdx.x * per;
    int en = s + per < E ? s + per : E;
    for (int e = s + threadIdx.x; e < en; e += blockDim.x) {
        int src = load_idx(ei, is64, (size_t)E + e);
        atomicAdd(&lh[src >> BSHIFT], 1u);
    }
    __syncthreads();
    for (int i = threadIdx.x; i < NBMAX; i += blockDim.x)
        lbase[i] = lh[i] ? atomicAdd(&bcursor[i], lh[i]) : 0u;
    __syncthreads();
    for (int e = s + threadIdx.x; e < en; e += blockDim.x) {
        int src = load_idx(ei, is64, (size_t)E + e);
        int b = src >> BSHIFT;
        unsigned pos = lbase[b] + atomicAdd(&lcur[b], 1u);
        perm[pos] = e;
        ssrc[pos] = src;
    }
}

// K2 (r9-exact): per (edge, head-pair) exp + ONE pk bf16 atomic; track max.
__global__ void edge_exp_sum_pk_kernel(const void* __restrict__ ei,
                                       const int* __restrict__ flag,
                                       const float* __restrict__ ss,
                                       const float* __restrict__ st,
                                       float* __restrict__ pbuf,
                                       unsigned* __restrict__ nsum_pk,
                                       unsigned* __restrict__ gmax,
                                       int E) {
    __shared__ float red[256];
    int is64 = *flag;
    int n2 = E * 2;
    int stride = gridDim.x * blockDim.x;
    float lmax = -__builtin_inff();
    for (int i = blockIdx.x * blockDim.x + threadIdx.x; i < n2; i += stride) {
        int e = i >> 1, hp = i & 1;
        int trg = load_idx(ei, is64, e);
        int src = load_idx(ei, is64, (size_t)E + e);
        f32x2 a = *(const f32x2*)(ss + (size_t)src * 4 + hp * 2);
        f32x2 b = *(const f32x2*)(st + (size_t)trg * 4 + hp * 2);
        float s0 = a.x + b.x, s1 = a.y + b.y;
        float lr0 = s0 > 0.f ? s0 : NEG_SLOPE * s0;
        float lr1 = s1 > 0.f ? s1 : NEG_SLOPE * s1;
        lmax = fmaxf(lmax, fmaxf(lr0, lr1));
        float p0 = __expf(lr0), p1 = __expf(lr1);
        f32x2 pv; pv.x = p0; pv.y = p1;
        __builtin_nontemporal_store(pv, (f32x2*)(pbuf + (size_t)e * 4 + hp * 2));
        pk_atomic_add_bf16(nsum_pk + (size_t)trg * 2 + hp, p0, p1);
    }
    red[threadIdx.x] = lmax;
    __syncthreads();
    for (int off = 128; off > 0; off >>= 1) {
        if (threadIdx.x < off)
            red[threadIdx.x] = fmaxf(red[threadIdx.x], red[threadIdx.x + off]);
        __syncthreads();
    }
    if (threadIdx.x == 0) atomicMax(gmax, fenc(red[0]));
}

// K3 (r9-exact): att = p / (bf16_decode(nsum) + eps*e^c).
__global__ void att_pk_kernel(const void* __restrict__ ei,
                              const int* __restrict__ flag,
                              const float* __restrict__ pbuf,
                              const unsigned* __restrict__ nsum_pk,
                              const unsigned* __restrict__ gmax,
                              float* __restrict__ out,
                              int E) {
    int is64 = *flag;
    float de = EPSV * __expf(fdec(*gmax));
    int stride = gridDim.x * blockDim.x;
    for (int e = blockIdx.x * blockDim.x + threadIdx.x; e < E; e += stride) {
        int trg = load_idx(ei, is64, e);
        u32x2 u = *(const u32x2*)(nsum_pk + (size_t)trg * 2);
        f32x4 d;
        d.x = __uint_as_float((u.x & 0xFFFFu) << 16);
        d.y = __uint_as_float(u.x & 0xFFFF0000u);
        d.z = __uint_as_float((u.y & 0xFFFFu) << 16);
        d.w = __uint_as_float(u.y & 0xFFFF0000u);
        f32x4 p = __builtin_nontemporal_load((const f32x4*)(pbuf + (size_t)e * 4));
        f32x4 a = p / (d + de);
        __builtin_nontemporal_store(a, (f32x4*)(out + (size_t)e * 4));
    }
}

// K4: bucket-ordered gather. Bucket c handled ONLY by XCD c%8 (blockIdx%8
// round-robin) -> each 128KB bucket is fetched ~once into one XCD's L2.
// Reads cached; writes nt, full-line (512B contiguous per edge).
__global__ void gather_sorted_kernel(const unsigned* __restrict__ bstart,
                                     const int* __restrict__ perm,
                                     const int* __restrict__ ssrc,
                                     const f32x4* __restrict__ nf4,
                                     f32x4* __restrict__ out4, int nb) {
    int xcd = blockIdx.x & 7;
    int lb = blockIdx.x >> 3;
    int lstride = (gridDim.x >> 3) * blockDim.x;
    for (int c = xcd; c < nb; c += 8) {
        int js = (int)bstart[c];
        int n = ((int)bstart[c + 1] - js) << 5;
        for (int t = lb * blockDim.x + threadIdx.x; t < n; t += lstride) {
            int j = js + (t >> 5), q = t & 31;
            int e = perm[j];
            int src = ssrc[j];
            f32x4 v = nf4[(size_t)src * 32 + q];
            __builtin_nontemporal_store(v, &out4[(size_t)e * 32 + q]);
        }
    }
}

// K4-fallback (r9-exact): linear gather.
__global__ void gather_feat_kernel(const void* __restrict__ ei,
                                   const int* __restrict__ flag,
                                   const f32x4* __restrict__ nf4,
                                   f32x4* __restrict__ out4, int E) {
    int is64 = *flag;
    int n = E * 32;
    int stride = gridDim.x * blockDim.x;
    for (int t = blockIdx.x * blockDim.x + threadIdx.x; t < n; t += stride) {
        int e = t >> 5, q = t & 31;
        int src = load_idx(ei, is64, (size_t)E + e);
        f32x4 v = nf4[(size_t)src * 32 + q];
        __builtin_nontemporal_store(v, &out4[(size_t)e * 32 + q]);
    }
}

// ---------- minimal-ws fallback pipeline ----------
__device__ __forceinline__ float edge_lr_rc(const void* ei, int is64,
                                            const float* ss, const float* st,
                                            int E, int e, int h, int* trg_out) {
    int trg = load_idx(ei, is64, e);
    int src = load_idx(ei, is64, (size_t)E + e);
    if (trg_out) *trg_out = trg;
    float s = ss[src * 4 + h] + st[trg * 4 + h];
    return s > 0.f ? s : NEG_SLOPE * s;
}

__global__ void zero_fb_kernel(float* __restrict__ nsum, int n) {
    int i = blockIdx.x * blockDim.x + threadIdx.x;
    if (i < n) nsum[i] = 0.f;
}

__global__ void edge_exp_sum_fb_kernel(const void* __restrict__ ei,
                                       const int* __restrict__ flag,
                                       const float* __restrict__ ss,
                                       const float* __restrict__ st,
                                       float* __restrict__ nsum,
                                       unsigned* __restrict__ gmax, int E) {
    __shared__ float red[256];
    int is64 = *flag;
    int n4 = E * 4;
    int stride = gridDim.x * blockDim.x;
    float lmax = -__builtin_inff();
    for (int i = blockIdx.x * blockDim.x + threadIdx.x; i < n4; i += stride) {
        int trg;
        float lr = edge_lr_rc(ei, is64, ss, st, E, i >> 2, i & 3, &trg);
        lmax = fmaxf(lmax, lr);
        atomicAdd(&nsum[trg * 4 + (i & 3)], __expf(lr));
    }
    red[threadIdx.x] = lmax;
    __syncthreads();
    for (int off = 128; off > 0; off >>= 1) {
        if (threadIdx.x < off)
            red[threadIdx.x] = fmaxf(red[threadIdx.x], red[threadIdx.x + off]);
        __syncthreads();
    }
    if (threadIdx.x == 0) atomicMax(gmax, fenc(red[0]));
}

__global__ void att_fb_kernel(const void* __restrict__ ei,
                              const int* __restrict__ flag,
                              const float* __restrict__ ss,
                              const float* __restrict__ st,
                              const unsigned* __restrict__ gmax,
                              const float* __restrict__ nsum,
                              float* __restrict__ out, int E) {
    int i = blockIdx.x * blockDim.x + threadIdx.x;
    if (i >= E * 4) return;
    int is64 = *flag;
    float de = EPSV * __expf(fdec(*gmax));
    int trg;
    float lr = edge_lr_rc(ei, is64, ss, st, E, i >> 2, i & 3, &trg);
    float a = __expf(lr) / (nsum[trg * 4 + (i & 3)] + de);
    __builtin_nontemporal_store(a, &out[i]);
}

extern "C" void kernel_launch(void* const* d_in, const int* in_sizes, int n_in,
                              void* d_out, int out_size, void* d_ws, size_t ws_size,
                              hipStream_t stream) {
    const float* nf  = (const float*)d_in[0];
    const float* sfs = (const float*)d_in[1];
    const float* sft = (const float*)d_in[2];
    const void*  ei  = d_in[3];

    const int NH = in_sizes[0] / 32;   // N*H (F = 32)
    const int N  = NH / 4;
    const int E  = in_sizes[3] / 2;
    const int nb = (N + (1 << BSHIFT) - 1) >> BSHIFT;   // actual bucket count

    float* out = (float*)d_out;
    float* ws  = (float*)d_ws;

    // Layout (words): ss[NH] | st[NH] | flag,gmax,pad,pad | pbuf[E*4]
    //   | nsum_pk[N*2] | bhist[NBMAX] | bstart[NBMAX+1] | bcursor[NBMAX]
    //   | perm[E] | ssrc[E]
    float*    ss      = ws;
    float*    st      = ws + NH;
    int*      flag    = (int*)(ws + 2 * (size_t)NH);
    unsigned* gmax    = (unsigned*)(flag + 1);
    float*    pbuf    = ws + 2 * (size_t)NH + 4;
    unsigned* nsum_pk = (unsigned*)(pbuf + (size_t)E * 4);
    unsigned* bhist   = nsum_pk + (size_t)N * 2;
    unsigned* bstart  = bhist + NBMAX;
    unsigned* bcursor = bstart + NBMAX + 1;
    int*      perm    = (int*)(bcursor + NBMAX);
    int*      ssrc    = perm + E;

    size_t need_r9   = ((size_t)2 * NH + 4 + (size_t)E * 4 + (size_t)N * 2) * 4;
    size_t need_sort = need_r9 + ((size_t)3 * NBMAX + 1 + (size_t)E * 2) * 4;
    bool lean = ws_size >= need_r9;
    bool srt  = ws_size >= need_sort;

    const int B = 256;

    detect_idx_kernel<<<1, 256, 0, stream>>>((const unsigned*)ei, flag, bhist);

    if (lean) {
        node_scores_kernel<<<(NH + B - 1) / B, B, 0, stream>>>(
            nf, sfs, sft, ss, st, nsum_pk, gmax, NH, N * 2);
        if (srt) {
            bin_hist_kernel<<<256, B, 0, stream>>>(ei, flag, bhist, E);
            bin_scan_kernel<<<1, 64, 0, stream>>>(bhist, bstart, bcursor, nb);
            bin_scatter_kernel<<<256, B, 0, stream>>>(ei, flag, bcursor, perm, ssrc, E);
        }
        edge_exp_sum_pk_kernel<<<2048, B, 0, stream>>>(ei, flag, ss, st, pbuf,
                                                       nsum_pk, gmax, E);
        att_pk_kernel<<<2048, B, 0, stream>>>(ei, flag, pbuf, nsum_pk, gmax,
                                              out, E);
        if (srt) {
            gather_sorted_kernel<<<4096, B, 0, stream>>>(
                bstart, perm, ssrc, (const f32x4*)nf,
                (f32x4*)(out + (size_t)E * 4), nb);
        } else {
            gather_feat_kernel<<<4096, B, 0, stream>>>(
                ei, flag, (const f32x4*)nf, (f32x4*)(out + (size_t)E * 4), E);
        }
    } else {
        float* nsum_fb = (float*)(gmax + 1);
        node_scores_kernel<<<(NH + B - 1) / B, B, 0, stream>>>(
            nf, sfs, sft, ss, st, (unsigned*)nsum_fb, gmax, NH, 0);
        zero_fb_kernel<<<(NH + B - 1) / B, B, 0, stream>>>(nsum_fb, NH);
        edge_exp_sum_fb_kernel<<<2048, B, 0, stream>>>(ei, flag, ss, st,
                                                       nsum_fb, gmax, E);
        att_fb_kernel<<<(E * 4 + B - 1) / B, B, 0, stream>>>(ei, flag, ss, st,
                                                             gmax, nsum_fb, out, E);
        gather_feat_kernel<<<4096, B, 0, stream>>>(
            ei, flag, (const f32x4*)nf, (f32x4*)(out + (size_t)E * 4), E);
    }
}